// Round 1
// 143.252 us; speedup vs baseline: 1.1084x; 1.1084x over previous
//
#include <hip/hip_runtime.h>
#include <float.h>

// Problem constants (match reference)
constexpr int H = 1024, W = 1024, C = 128, N_ITER = 8;
constexpr int TPB = 256;          // threads per block
constexpr int TILE = 32;          // 32x32 pixel tile per block
constexpr int PPT = 4;            // pixels (consecutive cols) per thread
constexpr int K = 32;             // atomic shards (contention depth 1024/K = 32)
constexpr int SLOTS = 2 * C;      // 256 accumulator slots

// Round-3 lesson: atomic-contention-bound -> 32-way sharding (kept).
// Round-4 (this round): the per-block critical path was dominated by the
// O(C) DEPENDENT-LDS dedup loop (`for j<tid { read cls[j]; if == break; }`):
// thread 127 walks 127 serial ds_read->cmp->branch iterations (~50-120cy
// each, the `break` defeats pipelining), between two barriers, on only 2 of
// 4 waves. Replaced with an all-pairs scan spread over ALL 256 threads:
// every unordered pair {i,j} is covered as (i,(i+k)&127), k=1..64; threads
// 0..127 take k=1..32, threads 128..255 take k=33..64 -> 32 INDEPENDENT
// (pipelinable) LDS reads per thread, overlapped with the phase-1a
// butterfly. A matching pair sets dupf[max(i,j)]=1 (same-value byte write,
// benign race). The keep-predicate "exists j<tid with cls[j]==cls[tid]" is
// computed exactly as before -> bit-identical results.
//
// One block per 32x32 tile.
// Phase 0: reconstruct cluster coords = sum of prev iteration's 32 shards
//          (iter 0 reads the input directly).
// Phase 1a: distance-to-tile-center + per-wave min (threads 0..127),
//           concurrently (all 256 threads): parallel coincident-cluster
//           dedup into dupf[]. Dedup is essential: from iter 3 on,
//           segment_sum leaves ~127 empty segments at exactly (0,0).
// Phase 1b: exact triangle-inequality prune (keep c iff d_c(center) <=
//           d_min + 2r + 1) && !dupf. Ballot+prefix compaction preserves
//           ascending index -> strict-'<' argmin tie-break unchanged.
// Phase 2: argmin over the ~2-6 surviving candidates.
// Epilogue: wave-uniform fast path (butterfly + 1 atomic) else per-lane LDS
// atomics; then ONE global atomic per nonzero slot per block into this
// block's shard (skip acc==0: contributions are >=+0.0, no -0.0 hazard).
__global__ __launch_bounds__(TPB) void kmeans_step(
    const float* __restrict__ cur0,        // [SLOTS] input clusters (iter 0 only)
    const float* __restrict__ prevShards,  // [K][SLOTS] prev iter shards (null on iter 0)
    const float* __restrict__ heatmap,     // [H,W]
    float* __restrict__ outShards)         // [K][SLOTS] this iter's shards (pre-zeroed)
{
    __shared__ float2 cls[C];              // aliased as float[SLOTS]
    __shared__ float2 cand[C];
    __shared__ int    candIdx[C];
    __shared__ float  waveMin[2];
    __shared__ int    waveCnt[2];
    __shared__ float  acc[SLOTS];          // SLOTS == 256 == TPB
    __shared__ unsigned char dupf[C];      // 1 = has a lower-indexed twin

    const int tid   = threadIdx.x;
    const int tileR = (blockIdx.x >> 5) * TILE;
    const int tileC = (blockIdx.x & 31) * TILE;

    acc[tid] = 0.0f;
    if (tid < C) dupf[tid] = 0;

    // ---- phase 0: materialize current cluster coords into LDS ----
    float coord;
    if (prevShards) {
        float s = 0.0f;
#pragma unroll
        for (int k = 0; k < K; ++k) s += prevShards[k * SLOTS + tid];
        coord = s;
    } else {
        coord = cur0[tid];
    }
    ((float*)cls)[tid] = coord;
    __syncthreads();

    // ---- phase 1a: center-distance + wave min (threads 0..127)
    //      concurrently: all-pairs coincidence scan (all 256 threads) ----
    const int    di  = tid & (C - 1);
    const float2 dme = cls[di];

    float dcen = 0.0f;
    if (tid < C) {
        const float dxr = dme.x - ((float)tileR + 15.5f);
        const float dyc = dme.y - ((float)tileC + 15.5f);
        dcen = sqrtf(dxr * dxr + dyc * dyc);
        float m = dcen;
#pragma unroll
        for (int off = 32; off > 0; off >>= 1)
            m = fminf(m, __shfl_xor(m, off));
        if ((tid & 63) == 0) waveMin[tid >> 6] = m;
    }

    {
        // pairs (di, (di+k)&127): k=1..32 on waves 0/1, k=33..64 on waves 2/3.
        // 32 independent LDS reads/thread -> pipelined, no dependent chain.
        const int kLo = (tid < C) ? 1 : 33;
#pragma unroll 8
        for (int kk = 0; kk < 32; ++kk) {
            const int k = kLo + kk;
            const int j = (di + k) & (C - 1);
            const float2 o = cls[j];
            if (o.x == dme.x && o.y == dme.y)
                dupf[(di + k < C) ? (di + k) : di] = 1;  // mark HIGHER index
        }
    }
    __syncthreads();

    // ---- phase 1b: prune + dedup-flag + ballot prefix (order-preserving) ----
    bool keep = false;
    int  pre  = 0;
    if (tid < C) {
        // 2*r_tile = 2*15.5*sqrt(2) = 43.84062; +1.0 clamp/rounding margin
        const float thr = fminf(waveMin[0], waveMin[1]) + 44.84062f;
        keep = (dcen <= thr) && (dupf[tid] == 0);
        const unsigned long long mask = __ballot(keep);
        const int lane = tid & 63;
        pre = __popcll(mask & ((1ull << lane) - 1ull));
        if (lane == 0) waveCnt[tid >> 6] = __popcll(mask);
    }
    __syncthreads();
    if (keep) {
        const int pos = pre + ((tid >= 64) ? waveCnt[0] : 0);
        cand[pos]    = cls[tid];
        candIdx[pos] = tid;
    }
    __syncthreads();

    const int nCand = waveCnt[0] + waveCnt[1];   // >= 1 always (nearest kept)

    // ---- phase 2: pruned argmin over candidates ----
    const int   rowIn = tid >> 3;                         // 0..31
    const float fr    = (float)(tileR + rowIn);
    const int   col0  = tileC + (tid & 7) * PPT;
    const float4 h4   = *(const float4*)(heatmap + (size_t)(tileR + rowIn) * W + col0);

    float hval[PPT] = { h4.x, h4.y, h4.z, h4.w };
    float colf[PPT], best[PPT];
    int   bi[PPT];
#pragma unroll
    for (int p = 0; p < PPT; ++p) {
        colf[p] = (float)(col0 + p);
        best[p] = FLT_MAX;
        bi[p]   = 0;
    }

    for (int k = 0; k < nCand; ++k) {
        const float2 cl = cand[k];                        // wave-uniform broadcast
        const int    ci = candIdx[k];
        const float  dx  = fr - cl.x;
        const float  dx2 = dx * dx;                       // row-constant, reused x4
#pragma unroll
        for (int p = 0; p < PPT; ++p) {
            const float dy  = colf[p] - cl.y;
            const float d2  = fmaf(dy, dy, dx2);
            const float key = fmaxf(d2, 1.0f);            // clamp before compare
            const bool  lt  = key < best[p];              // strict <: first-index ties
            bi[p]   = lt ? ci  : bi[p];
            best[p] = lt ? key : best[p];
        }
    }

    // ---- epilogue: 1 sqrt/pixel; wave-uniform reduce fast path; LDS scatter ----
#pragma unroll
    for (int p = 0; p < PPT; ++p) {
        const float bd  = fmaxf(1.0f, sqrtf(best[p]));    // = max(1, sqrt(d2))
        const float wgt = hval[p] / bd;
        float v0 = fr      * wgt;
        float v1 = colf[p] * wgt;
        const int b0 = __shfl(bi[p], 0);
        if (__ballot(bi[p] == b0) == 0xFFFFFFFFFFFFFFFFull) {
            // all 64 lanes agree: butterfly-sum, single atomic from lane 0
#pragma unroll
            for (int off = 32; off > 0; off >>= 1) {
                v0 += __shfl_xor(v0, off);
                v1 += __shfl_xor(v1, off);
            }
            if ((tid & 63) == 0) {
                unsafeAtomicAdd(&acc[2 * b0 + 0], v0);
                unsafeAtomicAdd(&acc[2 * b0 + 1], v1);
            }
        } else {
            unsafeAtomicAdd(&acc[2 * bi[p] + 0], v0);
            unsafeAtomicAdd(&acc[2 * bi[p] + 1], v1);
        }
    }
    __syncthreads();

    // one global atomic per NONZERO slot into this block's shard.
    // (contributions are all >= +0.0 and the shard is pre-zeroed to +0.0,
    //  so skipping +0.0 adds is exact.)
    const float a = acc[tid];
    if (a != 0.0f)
        unsafeAtomicAdd(&outShards[(blockIdx.x & (K - 1)) * SLOTS + tid], a);
}

// Sum the last iteration's shards into d_out. One block.
__global__ __launch_bounds__(SLOTS) void kmeans_finalize(
    const float* __restrict__ shards,      // [K][SLOTS]
    float* __restrict__ out)               // [SLOTS]
{
    const int tid = threadIdx.x;
    float s = 0.0f;
#pragma unroll
    for (int k = 0; k < K; ++k) s += shards[k * SLOTS + tid];
    out[tid] = s;
}

extern "C" void kernel_launch(void* const* d_in, const int* in_sizes, int n_in,
                              void* d_out, int out_size, void* d_ws, size_t ws_size,
                              hipStream_t stream) {
    const float* clusters = (const float*)d_in[0];  // [C,2] = 256 floats
    const float* heatmap  = (const float*)d_in[1];  // [H,W] = 1M floats
    float* out = (float*)d_out;                     // [C,2] = 256 floats

    // d_ws layout: 8 per-iteration shard buffers, each [K][SLOTS] floats.
    float* shards = (float*)d_ws;                   // 8 * 32 * 256 * 4B = 256 KB
    const size_t perIter = (size_t)K * SLOTS;

    // zero ALL shard buffers once (harness re-poisons d_ws before every launch)
    hipMemsetAsync(shards, 0, N_ITER * perIter * sizeof(float), stream);

    for (int it = 0; it < N_ITER; ++it) {
        const float* prev = (it == 0) ? nullptr : (shards + (it - 1) * perIter);
        float* dst = shards + it * perIter;
        kmeans_step<<<H, TPB, 0, stream>>>(clusters, prev, heatmap, dst);
    }
    kmeans_finalize<<<1, SLOTS, 0, stream>>>(shards + (N_ITER - 1) * perIter, out);
}